// Round 1
// baseline (3362.073 us; speedup 1.0000x reference)
//
#include <hip/hip_runtime.h>
#include <hip/hip_bf16.h>

typedef short short8_v __attribute__((ext_vector_type(8)));
typedef float f32x4 __attribute__((ext_vector_type(4)));

#define GB 256           // gemm blocks at the front of stepA's grid
#define NTAPE_BLKS 1024  // 1024 blocks x 2 waves = 2048 (b,tape) pairs
#define QC 576           // padded qkva column stride

// fragment-swizzled layout: element (r,k) of an [R][K] operand ->
// tile (r/16, k/32), lane = (r%16) + 16*((k%32)/8), elem = k%8
__device__ __forceinline__ size_t swz_e(int r, int k, int KC) {
  return ((size_t)((r >> 4) * KC + (k >> 5)) * 64 + (r & 15) + (((k >> 3) & 3) << 4)) * 8 + (k & 7);
}

__device__ __forceinline__ float wave_sum(float v) {
#pragma unroll
  for (int off = 32; off > 0; off >>= 1) v += __shfl_xor(v, off);
  return v;
}

__device__ __forceinline__ float sigf(float x) { return 1.f / (1.f + __expf(-x)); }

// ---------------- prologue kernels (once per call) ----------------

// Wcat[jj][k] (bf16, swizzled), jj gate-interleaved: jj = 64*chunk + 16*gate + r,
// orig row j = 256*gate + 16*chunk + r ; k<256 -> W_ih, k>=256 -> W_hh
__global__ void prep_weights(const float* __restrict__ W_ih, const float* __restrict__ W_hh,
                             __hip_bfloat16* __restrict__ Wcat) {
  int idx = blockIdx.x * blockDim.x + threadIdx.x;  // 1024*512
  if (idx >= 1024 * 512) return;
  int jj = idx >> 9, k = idx & 511;
  int chunk = jj >> 6, gate = (jj >> 4) & 3, r = jj & 15;
  int j = gate * 256 + chunk * 16 + r;
  float v = (k < 256) ? W_ih[j * 256 + k] : W_hh[j * 256 + (k - 256)];
  Wcat[swz_e(jj, k, 16)] = __float2bfloat16(v);
}

// Wq rows remapped: n<256 -> query rows 0..255 ; 256<=n<556 -> orig n+256
// (value rows 512..767 and action rows 768..811) ; 556..575 zero pad
__global__ void prep_wq(const float* __restrict__ Wq_w, const float* __restrict__ Wq_b,
                        __hip_bfloat16* __restrict__ Wq, float* __restrict__ biasq) {
  int idx = blockIdx.x * blockDim.x + threadIdx.x;  // 576*256
  if (idx >= 576 * 256) return;
  int n = idx >> 8, k = idx & 255;
  int orig = (n < 256) ? n : (n < 556 ? n + 256 : -1);
  float v = (orig >= 0) ? Wq_w[orig * 256 + k] : 0.f;
  Wq[swz_e(n, k, 8)] = __float2bfloat16(v);
  if (k == 0) biasq[n] = (orig >= 0) ? Wq_b[orig] : 0.f;
}

__global__ void prep_tgt(const float* __restrict__ tgt, __hip_bfloat16* __restrict__ tswz) {
  for (size_t idx = (size_t)blockIdx.x * blockDim.x + threadIdx.x; idx < (size_t)128 * 131072;
       idx += (size_t)gridDim.x * blockDim.x) {
    int t = (int)(idx >> 17);
    int rem = (int)(idx & 131071);
    int b = rem >> 8, k = rem & 255;
    tswz[(size_t)t * 131072 + swz_e(b, k, 8)] = __float2bfloat16(tgt[idx]);
  }
}

__global__ void prep_init(const float* __restrict__ src, float* __restrict__ tape,
                          float* __restrict__ rpos, float* __restrict__ wpos,
                          float* __restrict__ cst, __hip_bfloat16* __restrict__ h0,
                          __hip_bfloat16* __restrict__ h1) {
  for (size_t idx = (size_t)blockIdx.x * blockDim.x + threadIdx.x; idx < (size_t)8388608;
       idx += (size_t)gridDim.x * blockDim.x) {
    int bt = (int)(idx >> 12), l = (int)(idx >> 6) & 63, cc = (int)idx & 63;
    int b = bt >> 2, tp = bt & 3;
    tape[idx] = src[(size_t)l * 131072 + b * 256 + tp * 64 + cc];
    if (idx < 131072) {
      int l2 = (int)idx & 63;
      float v = (l2 == 0) ? 1.f : 0.f;
      rpos[idx] = v;
      wpos[idx] = v;
      cst[idx] = 0.f;
      h0[idx] = __float2bfloat16(0.f);
      h1[idx] = __float2bfloat16(0.f);
    }
  }
}

// ---------------- per-step kernel A: gates GEMM+LSTM (t)  ||  tape update (t-1) ----------------

__global__ __launch_bounds__(128) void stepA(
    const short8_v* __restrict__ xg_t,   // tgt_swz for step t   [32][8][64] short8
    const short8_v* __restrict__ Wcat,   // [64][16][64] short8
    const short8_v* __restrict__ h_in,   // h(t-1) swizzled      [16][8][64] short8
    __hip_bfloat16* __restrict__ h_out,  // h(t) swizzled
    float* __restrict__ cst, const float* __restrict__ b_ih, const float* __restrict__ b_hh,
    const float* __restrict__ qkva,      // qkva(t-1) [512][QC]
    float* __restrict__ tape, float* __restrict__ rpos, float* __restrict__ wpos,
    float* __restrict__ out_t,           // out row for step t-1
    int do_gates, int do_tape) {
  __shared__ float lds[2 * 4352];  // per-wave: T[64][65] + w[64] + rr[64] + q[64]
  int blk = blockIdx.x;
  int wid = threadIdx.x >> 6;
  int lane = threadIdx.x & 63;

  if (blk < GB) {
    if (!do_gates) return;
    int mblk = blk >> 4;  // 0..15
    int cb = blk & 15;    // j0 chunk 0..15
    int m16 = mblk * 2 + wid;
    f32x4 acc0 = {0.f, 0.f, 0.f, 0.f}, acc1 = acc0, acc2 = acc0, acc3 = acc0;
    for (int kc = 0; kc < 16; ++kc) {
      short8_v a = (kc < 8) ? xg_t[(m16 * 8 + kc) * 64 + lane]
                            : h_in[(m16 * 8 + kc - 8) * 64 + lane];
      short8_v b0 = Wcat[((4 * cb + 0) * 16 + kc) * 64 + lane];
      short8_v b1 = Wcat[((4 * cb + 1) * 16 + kc) * 64 + lane];
      short8_v b2 = Wcat[((4 * cb + 2) * 16 + kc) * 64 + lane];
      short8_v b3 = Wcat[((4 * cb + 3) * 16 + kc) * 64 + lane];
      acc0 = __builtin_amdgcn_mfma_f32_16x16x32_bf16(a, b0, acc0, 0, 0, 0);
      acc1 = __builtin_amdgcn_mfma_f32_16x16x32_bf16(a, b1, acc1, 0, 0, 0);
      acc2 = __builtin_amdgcn_mfma_f32_16x16x32_bf16(a, b2, acc2, 0, 0, 0);
      acc3 = __builtin_amdgcn_mfma_f32_16x16x32_bf16(a, b3, acc3, 0, 0, 0);
    }
    int j0 = cb * 16 + (lane & 15);
    float bi = b_ih[j0] + b_hh[j0];
    float bf = b_ih[256 + j0] + b_hh[256 + j0];
    float bg = b_ih[512 + j0] + b_hh[512 + j0];
    float bo = b_ih[768 + j0] + b_hh[768 + j0];
#pragma unroll
    for (int r = 0; r < 4; ++r) {
      int brow = m16 * 16 + ((lane >> 4) << 2) + r;
      float si = sigf(acc0[r] + bi);
      float sf = sigf(acc1[r] + bf);
      float tg = tanhf(acc2[r] + bg);
      float so = sigf(acc3[r] + bo);
      int cidx = brow * 256 + j0;
      float cc = sf * cst[cidx] + si * tg;
      cst[cidx] = cc;
      float hh = so * tanhf(cc);
      h_out[swz_e(brow, j0, 8)] = __float2bfloat16(hh);
    }
  } else {
    if (!do_tape) return;
    int bt = (blk - GB) * 2 + wid;  // 0..2047
    int b = bt >> 2, tp = bt & 3;
    float* T = lds + wid * 4352;
    float* ws_ = T + 4160;
    float* rs_ = ws_ + 64;
    float* qs_ = rs_ + 64;
    const float* qrow = qkva + b * QC;

    float a_[11];
#pragma unroll
    for (int j = 0; j < 11; ++j) a_[j] = qrow[512 + tp * 11 + j];
    // read_dir = softmax(a0..a3), write_dir = softmax(a4..a7), rwe = sigmoid(a8..a10)
    float m1 = fmaxf(fmaxf(a_[0], a_[1]), fmaxf(a_[2], a_[3]));
    float e0 = __expf(a_[0] - m1), e1 = __expf(a_[1] - m1), e2 = __expf(a_[2] - m1),
          e3 = __expf(a_[3] - m1);
    float inv = 1.f / (e0 + e1 + e2 + e3);
    float rd0 = e0 * inv, rd1 = e1 * inv, rd2 = e2 * inv, rd3 = e3 * inv;
    float m2 = fmaxf(fmaxf(a_[4], a_[5]), fmaxf(a_[6], a_[7]));
    float f0 = __expf(a_[4] - m2), f1 = __expf(a_[5] - m2), f2 = __expf(a_[6] - m2),
          f3 = __expf(a_[7] - m2);
    float inv2 = 1.f / (f0 + f1 + f2 + f3);
    float wd0 = f0 * inv2, wd1 = f1 * inv2, wd2 = f2 * inv2, wd3 = f3 * inv2;
    float rwe0 = sigf(a_[8]), rwe1 = sigf(a_[9]), rwe2 = sigf(a_[10]);

    float q = qrow[tp * 64 + lane];
    float ssum = wave_sum(q * q);
    float qn = q / fmaxf(sqrtf(ssum), 1e-12f);
    float val = qrow[256 + tp * 64 + lane];
    float rp = rpos[bt * 64 + lane];
    float wp = wpos[bt * 64 + lane];
    ws_[lane] = wp;
    rs_[lane] = rp * rwe0;
    qs_[lane] = qn;
    __syncthreads();

    float* Tg = tape + (size_t)bt * 4096;
    float oldacc = 0.f, racc = 0.f;
    for (int l = 0; l < 64; ++l) {
      float v = Tg[l * 64 + lane];
      T[l * 65 + lane] = v;
      oldacc = fmaf(ws_[l], v, oldacc);
      racc = fmaf(rs_[l], v, racc);
    }
    __syncthreads();

    float jq = 0.f;
    for (int cc = 0; cc < 64; ++cc) jq = fmaf(T[lane * 65 + cc], qs_[cc], jq);
    float jsum = wave_sum(jq * jq);
    float jp = jq / fmaxf(sqrtf(jsum), 1e-12f);

    // roll(x,1)[i]=x[i-1] (next_*), roll(x,-1)[i]=x[i+1] (prev_*)
    float next_w = __shfl(wp, (lane + 63) & 63);
    float prev_w = __shfl(wp, (lane + 1) & 63);
    float next_r = __shfl(rp, (lane + 63) & 63);
    float prev_r = __shfl(rp, (lane + 1) & 63);
    wpos[bt * 64 + lane] = prev_w * wd0 + wp * wd1 + next_w * wd2 + jp * wd3;
    rpos[bt * 64 + lane] = prev_r * rd0 + rp * rd1 + next_r * rd2 + jp * rd3;

    float dv = val * rwe1 - oldacc * rwe2;
    for (int l = 0; l < 64; ++l) Tg[l * 64 + lane] = T[l * 65 + lane] + ws_[l] * dv;

    out_t[b * 256 + tp * 64 + lane] = racc;
  }
}

// ---------------- per-step kernel B: qkva GEMM ----------------

__global__ __launch_bounds__(128) void stepB(const short8_v* __restrict__ h_in,
                                             const short8_v* __restrict__ Wq,
                                             const float* __restrict__ biasq,
                                             float* __restrict__ qkva) {
  int blk = blockIdx.x;  // 144 = 16 mblk x 9 nb
  int mblk = blk / 9, nb = blk % 9;
  int wid = threadIdx.x >> 6, lane = threadIdx.x & 63;
  int m16 = mblk * 2 + wid;
  f32x4 acc0 = {0.f, 0.f, 0.f, 0.f}, acc1 = acc0, acc2 = acc0, acc3 = acc0;
  for (int kc = 0; kc < 8; ++kc) {
    short8_v a = h_in[(m16 * 8 + kc) * 64 + lane];
    short8_v b0 = Wq[((4 * nb + 0) * 8 + kc) * 64 + lane];
    short8_v b1 = Wq[((4 * nb + 1) * 8 + kc) * 64 + lane];
    short8_v b2 = Wq[((4 * nb + 2) * 8 + kc) * 64 + lane];
    short8_v b3 = Wq[((4 * nb + 3) * 8 + kc) * 64 + lane];
    acc0 = __builtin_amdgcn_mfma_f32_16x16x32_bf16(a, b0, acc0, 0, 0, 0);
    acc1 = __builtin_amdgcn_mfma_f32_16x16x32_bf16(a, b1, acc1, 0, 0, 0);
    acc2 = __builtin_amdgcn_mfma_f32_16x16x32_bf16(a, b2, acc2, 0, 0, 0);
    acc3 = __builtin_amdgcn_mfma_f32_16x16x32_bf16(a, b3, acc3, 0, 0, 0);
  }
#pragma unroll
  for (int r = 0; r < 4; ++r) {
    int brow = m16 * 16 + ((lane >> 4) << 2) + r;
    int n0 = (4 * nb + 0) * 16 + (lane & 15);
    int n1 = (4 * nb + 1) * 16 + (lane & 15);
    int n2 = (4 * nb + 2) * 16 + (lane & 15);
    int n3 = (4 * nb + 3) * 16 + (lane & 15);
    qkva[brow * QC + n0] = acc0[r] + biasq[n0];
    qkva[brow * QC + n1] = acc1[r] + biasq[n1];
    qkva[brow * QC + n2] = acc2[r] + biasq[n2];
    qkva[brow * QC + n3] = acc3[r] + biasq[n3];
  }
}

// ---------------- host ----------------

extern "C" void kernel_launch(void* const* d_in, const int* in_sizes, int n_in, void* d_out,
                              int out_size, void* d_ws, size_t ws_size, hipStream_t stream) {
  const float* tgt = (const float*)d_in[0];
  const float* src = (const float*)d_in[1];
  const float* W_ih = (const float*)d_in[2];
  const float* W_hh = (const float*)d_in[3];
  const float* b_ih = (const float*)d_in[4];
  const float* b_hh = (const float*)d_in[5];
  const float* Wq_w = (const float*)d_in[6];
  const float* Wq_b = (const float*)d_in[7];
  float* out = (float*)d_out;

  char* ws = (char*)d_ws;
  size_t off = 0;
  auto alloc = [&](size_t bytes) -> void* {
    void* p = ws + off;
    off = (off + bytes + 255) & ~(size_t)255;
    return p;
  };
  float* tape = (float*)alloc((size_t)2048 * 4096 * 4);
  float* rpos = (float*)alloc((size_t)2048 * 64 * 4);
  float* wpos = (float*)alloc((size_t)2048 * 64 * 4);
  float* cst = (float*)alloc((size_t)512 * 256 * 4);
  __hip_bfloat16* h0 = (__hip_bfloat16*)alloc((size_t)512 * 256 * 2);
  __hip_bfloat16* h1 = (__hip_bfloat16*)alloc((size_t)512 * 256 * 2);
  float* qkva = (float*)alloc((size_t)512 * QC * 4);
  __hip_bfloat16* Wcat = (__hip_bfloat16*)alloc((size_t)1024 * 512 * 2);
  __hip_bfloat16* Wq = (__hip_bfloat16*)alloc((size_t)576 * 256 * 2);
  float* biasq = (float*)alloc((size_t)576 * 4);
  __hip_bfloat16* tswz = (__hip_bfloat16*)alloc((size_t)128 * 131072 * 2);

  prep_weights<<<2048, 256, 0, stream>>>(W_ih, W_hh, Wcat);
  prep_wq<<<576, 256, 0, stream>>>(Wq_w, Wq_b, Wq, biasq);
  prep_tgt<<<8192, 256, 0, stream>>>(tgt, tswz);
  prep_init<<<8192, 256, 0, stream>>>(src, tape, rpos, wpos, cst, h0, h1);

  __hip_bfloat16* hb[2] = {h0, h1};
  for (int t = 0; t < 128; ++t) {
    stepA<<<GB + NTAPE_BLKS, 128, 0, stream>>>(
        (const short8_v*)(tswz + (size_t)t * 131072), (const short8_v*)Wcat,
        (const short8_v*)hb[(t + 1) & 1], hb[t & 1], cst, b_ih, b_hh, qkva, tape, rpos, wpos,
        out + (size_t)(t > 0 ? t - 1 : 0) * 131072, 1, (t > 0) ? 1 : 0);
    stepB<<<144, 128, 0, stream>>>((const short8_v*)hb[t & 1], (const short8_v*)Wq, biasq, qkva);
  }
  // final tape update for t=127
  stepA<<<GB + NTAPE_BLKS, 128, 0, stream>>>(
      (const short8_v*)tswz, (const short8_v*)Wcat, (const short8_v*)h0, h1, cst, b_ih, b_hh,
      qkva, tape, rpos, wpos, out + (size_t)127 * 131072, 0, 1);
}

// Round 3
// 1417.172 us; speedup vs baseline: 2.3724x; 2.3724x over previous
//
#include <hip/hip_runtime.h>
#include <hip/hip_bf16.h>

typedef short short8_v __attribute__((ext_vector_type(8)));
typedef float f32x4 __attribute__((ext_vector_type(4)));

#define QC 576  // padded qkva column stride: q[0,256) val[256,512) act[512,556) pad[556,576)

// fragment-swizzled layout: element (r,k) of an [R][K] operand ->
// tile (r/16, k/32), lane = (r%16) + 16*((k%32)/8), elem = k%8
__device__ __forceinline__ size_t swz_e(int r, int k, int KC) {
  return ((size_t)((r >> 4) * KC + (k >> 5)) * 64 + (r & 15) + (((k >> 3) & 3) << 4)) * 8 + (k & 7);
}

__device__ __forceinline__ float wave_sum(float v) {
#pragma unroll
  for (int off = 32; off > 0; off >>= 1) v += __shfl_xor(v, off);
  return v;
}

__device__ __forceinline__ float sigf(float x) { return 1.f / (1.f + __expf(-x)); }

// relaxed agent-scope atomics: bypass L1/L2, coherent at L3 across XCDs
template <typename T>
__device__ __forceinline__ T ald(const T* p) {
  return __hip_atomic_load(p, __ATOMIC_RELAXED, __HIP_MEMORY_SCOPE_AGENT);
}
template <typename T>
__device__ __forceinline__ void ast(T* p, T v) {
  __hip_atomic_store(p, v, __ATOMIC_RELAXED, __HIP_MEMORY_SCOPE_AGENT);
}

// ---------------- prologue kernels (once per call) ----------------

// Wcat[jj][k] (bf16, swizzled), jj gate-interleaved: jj = 64*chunk + 16*gate + r,
// orig row j = 256*gate + 16*chunk + r ; k<256 -> W_ih, k>=256 -> W_hh
__global__ void prep_weights(const float* __restrict__ W_ih, const float* __restrict__ W_hh,
                             __hip_bfloat16* __restrict__ Wcat) {
  int idx = blockIdx.x * blockDim.x + threadIdx.x;  // 1024*512
  if (idx >= 1024 * 512) return;
  int jj = idx >> 9, k = idx & 511;
  int chunk = jj >> 6, gate = (jj >> 4) & 3, r = jj & 15;
  int j = gate * 256 + chunk * 16 + r;
  float v = (k < 256) ? W_ih[j * 256 + k] : W_hh[j * 256 + (k - 256)];
  Wcat[swz_e(jj, k, 16)] = __float2bfloat16(v);
}

// Wq rows remapped: n<256 -> query rows 0..255 ; 256<=n<556 -> orig n+256 ; 556..575 zero
__global__ void prep_wq(const float* __restrict__ Wq_w, const float* __restrict__ Wq_b,
                        __hip_bfloat16* __restrict__ Wq, float* __restrict__ biasq) {
  int idx = blockIdx.x * blockDim.x + threadIdx.x;  // 576*256
  if (idx >= 576 * 256) return;
  int n = idx >> 8, k = idx & 255;
  int orig = (n < 256) ? n : (n < 556 ? n + 256 : -1);
  float v = (orig >= 0) ? Wq_w[orig * 256 + k] : 0.f;
  Wq[swz_e(n, k, 8)] = __float2bfloat16(v);
  if (k == 0) biasq[n] = (orig >= 0) ? Wq_b[orig] : 0.f;
}

__global__ void prep_tgt(const float* __restrict__ tgt, __hip_bfloat16* __restrict__ tswz) {
  for (size_t idx = (size_t)blockIdx.x * blockDim.x + threadIdx.x; idx < (size_t)128 * 131072;
       idx += (size_t)gridDim.x * blockDim.x) {
    int t = (int)(idx >> 17);
    int rem = (int)(idx & 131071);
    int b = rem >> 8, k = rem & 255;
    tswz[(size_t)t * 131072 + swz_e(b, k, 8)] = __float2bfloat16(tgt[idx]);
  }
}

__global__ void reset_bars(unsigned* __restrict__ bars) {
  int i = blockIdx.x * blockDim.x + threadIdx.x;
  if (i < 2048) bars[i] = 0u;
}

// ---------------- persistent cooperative kernel ----------------
// grid = 256 blocks x 512 threads. Group g = m (0..31) = blocks {m + 32*cgrp}.
// Block (m,cgrp): owns 8 tape pairs (b = 16m + 2*cgrp + {0,1}, tp 0..3, one per wave),
// computes gates slice (rows 16m..16m+16, h-cols [32*cgrp, 32*cgrp+32) all 4 gates) and
// qkva tiles [qst, qst+qcnt) for rows 16m.
// Phase p: gates(p)+LSTM -> h(p) || qkva(p-1) || tape(p-2). Group barrier per phase.
// LDS (floats): tape 8*[64][65] @0 ; sc 8*[64]f32x4 @33280 ; gbuf [2][4][16][16] @35328 ;
//               hstage [8][64][8]bf16 (as 2048 f) @37376 ; total 39424 f = 157696 B

#define DYN_LDS 157696

__global__ __launch_bounds__(512, 2) void persist(
    const short8_v* __restrict__ tswz, const short8_v* __restrict__ Wcat,
    const short8_v* __restrict__ Wq, const float* __restrict__ biasq,
    const float* __restrict__ b_ih, const float* __restrict__ b_hh,
    unsigned short* __restrict__ hG,   // 2 x 131072 bf16 (frag-swizzled), dbuf
    float* __restrict__ qkva,          // 2 x 512*QC f32, dbuf
    float* __restrict__ out, const float* __restrict__ src, unsigned* __restrict__ bars) {
  extern __shared__ float lds[];
  const int tid = threadIdx.x;
  const int w = tid >> 6, lane = tid & 63;
  const int m = blockIdx.x & 31, cgrp = blockIdx.x >> 5;
  unsigned* grpbar = bars + m * 64;

  float* T = lds + w * 4160;                       // this wave's tape [64][65]
  f32x4* scv = (f32x4*)(lds + 33280) + w * 64;     // {ws_pend, wp, rs, qn} per l
  float* gbuf = lds + 35328;                       // gates staging [2][4][16][16]
  unsigned long long* hstage_u64 = (unsigned long long*)(lds + 37376);
  const short8_v* hstage_s8 = (const short8_v*)(lds + 37376);

  // ---- tape pair identity + init ----
  const int b = 16 * m + 2 * cgrp + (w >> 2);
  const int tp = w & 3;
#pragma unroll 2
  for (int l = 0; l < 64; ++l)
    T[l * 65 + lane] = src[(size_t)l * 131072 + b * 256 + tp * 64 + lane];
  float rp = (lane == 0) ? 1.f : 0.f, wp = rp;
  float wsp = 0.f, dvp = 0.f;  // pending rank-1: tape_true = T + outer(wsp, dvp)

  // ---- epilogue-role regs: thread tid -> one h value (row = tid>>5, colLocal = tid&31) ----
  const int erow = tid >> 5, ecol = tid & 31;
  const int jh = 32 * cgrp + ecol;
  const float bI = b_ih[jh] + b_hh[jh];
  const float bF = b_ih[256 + jh] + b_hh[256 + jh];
  const float bG_ = b_ih[512 + jh] + b_hh[512 + jh];
  const float bO = b_ih[768 + jh] + b_hh[768 + jh];
  float c_reg = 0.f;
  // hG store slot (u32 units), pairs packed by even-ecol threads:
  const unsigned hIdx32 =
      (unsigned)(((m * 8 + cgrp) * 64 + erow + 16 * (ecol >> 3)) * 4 + ((ecol >> 1) & 3));

  // ---- qkva tile assignment ----
  const int qcnt = (cgrp < 4) ? 5 : 4;
  const int qst = (cgrp < 4) ? cgrp * 5 : 20 + (cgrp - 4) * 4;
  const int qtile = qst + w;  // valid if w < qcnt

#pragma unroll 1
  for (int p = 0; p <= 129; ++p) {
    const int hrd = (p + 1) & 1, hwr = p & 1;
    const int s = p - 2;  // tape step

    // ---- early issue: tape's qkva-row loads (L3) ----
    float q = 0.f, val = 0.f, a_[11];
    if (s >= 0) {
      const float* qrow = qkva + (size_t)(s & 1) * (512 * QC) + (size_t)b * QC;
#pragma unroll
      for (int j = 0; j < 11; ++j) a_[j] = ald(qrow + 512 + tp * 11 + j);
      q = ald(qrow + tp * 64 + lane);
      val = ald(qrow + 256 + tp * 64 + lane);
    }
    // ---- issue gates operand loads (read-only, cached) ----
    short8_v aF[8], bFr[16];
    if (p < 128) {
      const short8_v* xg = tswz + (size_t)p * 16384;
#pragma unroll
      for (int kc = 0; kc < 8; ++kc) aF[kc] = xg[(m * 8 + kc) * 64 + lane];
#pragma unroll
      for (int kc = 0; kc < 16; ++kc)
        bFr[kc] = Wcat[((cgrp * 8 + w) * 16 + kc) * 64 + lane];
    }
    // ---- stage h(p-1) into LDS: wave w stages k-chunk w (L3-coherent loads) ----
    if (p >= 1 && p <= 128) {
      const unsigned long long* hsrc = (const unsigned long long*)(hG + (size_t)hrd * 131072) +
                                       ((size_t)(m * 8 + w) * 64 + lane) * 2;
      unsigned long long lo = ald(hsrc), hi = ald(hsrc + 1);
      hstage_u64[((size_t)w * 64 + lane) * 2] = lo;
      hstage_u64[((size_t)w * 64 + lane) * 2 + 1] = hi;
    }
    // ---- tape compute for step s ----
    if (s >= 0) {
      float m1 = fmaxf(fmaxf(a_[0], a_[1]), fmaxf(a_[2], a_[3]));
      float e0 = __expf(a_[0] - m1), e1 = __expf(a_[1] - m1), e2 = __expf(a_[2] - m1),
            e3 = __expf(a_[3] - m1);
      float inv = 1.f / (e0 + e1 + e2 + e3);
      float rd0 = e0 * inv, rd1 = e1 * inv, rd2 = e2 * inv, rd3 = e3 * inv;
      float m2 = fmaxf(fmaxf(a_[4], a_[5]), fmaxf(a_[6], a_[7]));
      float f0 = __expf(a_[4] - m2), f1 = __expf(a_[5] - m2), f2 = __expf(a_[6] - m2),
            f3 = __expf(a_[7] - m2);
      float inv2 = 1.f / (f0 + f1 + f2 + f3);
      float wd0 = f0 * inv2, wd1 = f1 * inv2, wd2 = f2 * inv2, wd3 = f3 * inv2;
      float rwe0 = sigf(a_[8]), rwe1 = sigf(a_[9]), rwe2 = sigf(a_[10]);
      float qn = q / fmaxf(sqrtf(wave_sum(q * q)), 1e-12f);
      f32x4 scnew = {wsp, wp, rp * rwe0, qn};
      scv[lane] = scnew;
      // row pass: apply pending rank-1, write back, reduce oldval & rval
      float oldacc = 0.f, racc = 0.f;
#pragma unroll 4
      for (int l = 0; l < 64; ++l) {
        f32x4 f4 = scv[l];
        float v = fmaf(f4.x, dvp, T[l * 65 + lane]);
        T[l * 65 + lane] = v;
        oldacc = fmaf(f4.y, v, oldacc);
        racc = fmaf(f4.z, v, racc);
      }
      // col pass: jq over columns
      float jq = 0.f;
#pragma unroll 4
      for (int cc = 0; cc < 64; ++cc) jq = fmaf(T[lane * 65 + cc], scv[cc].w, jq);
      float jp = jq / fmaxf(sqrtf(wave_sum(jq * jq)), 1e-12f);
      // roll(x,1)[i]=x[i-1] (next_*), roll(x,-1)[i]=x[i+1] (prev_*)
      float next_w = __shfl(wp, (lane + 63) & 63);
      float prev_w = __shfl(wp, (lane + 1) & 63);
      float next_r = __shfl(rp, (lane + 63) & 63);
      float prev_r = __shfl(rp, (lane + 1) & 63);
      float wp_old = wp;
      wp = prev_w * wd0 + wp * wd1 + next_w * wd2 + jp * wd3;
      rp = prev_r * rd0 + rp * rd1 + next_r * rd2 + jp * rd3;
      wsp = wp_old;
      dvp = val * rwe1 - oldacc * rwe2;
      out[(size_t)s * 131072 + b * 256 + tp * 64 + lane] = racc;
    }
    __syncthreads();  // hstage ready; gbuf free
    // ---- gates MFMA + gbuf ----
    if (p < 128) {
      f32x4 acc = {0.f, 0.f, 0.f, 0.f};
#pragma unroll
      for (int kc = 0; kc < 8; ++kc)
        acc = __builtin_amdgcn_mfma_f32_16x16x32_bf16(aF[kc], bFr[kc], acc, 0, 0, 0);
      if (p > 0) {
#pragma unroll
        for (int kc = 8; kc < 16; ++kc) {
          short8_v a = hstage_s8[(kc - 8) * 64 + lane];
          acc = __builtin_amdgcn_mfma_f32_16x16x32_bf16(a, bFr[kc], acc, 0, 0, 0);
        }
      }
      int cl = w >> 2, gate = w & 3;
#pragma unroll
      for (int r = 0; r < 4; ++r)
        gbuf[((cl * 4 + gate) * 16 + ((lane >> 4) * 4 + r)) * 16 + (lane & 15)] = acc[r];
    }
    // ---- qkva B loads ----
    short8_v bQ[8];
    if (p >= 1 && p <= 128 && w < qcnt) {
#pragma unroll
      for (int kc = 0; kc < 8; ++kc) bQ[kc] = Wq[(qtile * 8 + kc) * 64 + lane];
    }
    __syncthreads();  // gbuf ready
    // ---- LSTM epilogue -> h(p): thread owns (row=erow, col=jh) ----
    if (p < 128) {
      float gi = gbuf[(((ecol >> 4) * 4 + 0) * 16 + erow) * 16 + (ecol & 15)] + bI;
      float gf = gbuf[(((ecol >> 4) * 4 + 1) * 16 + erow) * 16 + (ecol & 15)] + bF;
      float gg = gbuf[(((ecol >> 4) * 4 + 2) * 16 + erow) * 16 + (ecol & 15)] + bG_;
      float go = gbuf[(((ecol >> 4) * 4 + 3) * 16 + erow) * 16 + (ecol & 15)] + bO;
      float cc = sigf(gf) * c_reg + sigf(gi) * tanhf(gg);
      c_reg = cc;
      float hh = sigf(go) * tanhf(cc);
      __hip_bfloat16 hb16 = __float2bfloat16(hh);
      unsigned own = (unsigned)(*(unsigned short*)&hb16);
      unsigned other = (unsigned)__shfl_xor((int)own, 1) & 0xFFFFu;
      if ((ecol & 1) == 0) {
        unsigned pack = (other << 16) | own;
        ast((unsigned*)(hG + (size_t)hwr * 131072) + hIdx32, pack);
      }
    }
    // ---- qkva MFMA for step p-1 (A from hstage) ----
    if (p >= 1 && p <= 128 && w < qcnt) {
      f32x4 qa = {0.f, 0.f, 0.f, 0.f};
#pragma unroll
      for (int kc = 0; kc < 8; ++kc)
        qa = __builtin_amdgcn_mfma_f32_16x16x32_bf16(hstage_s8[kc * 64 + lane], bQ[kc], qa, 0, 0, 0);
      int n0 = qtile * 16 + (lane & 15);
      float bq = biasq[n0];
      float* qw = qkva + (size_t)((p - 1) & 1) * (512 * QC);
#pragma unroll
      for (int r = 0; r < 4; ++r)
        ast(&qw[(size_t)(16 * m + (lane >> 4) * 4 + r) * QC + n0], qa[r] + bq);
    }
    // ---- group barrier (monotonic arrival counter, no fences) ----
    if (p < 129) {
      __syncthreads();  // drains each wave's vmem stores before arrival
      if (tid == 0) {
        __hip_atomic_fetch_add(grpbar, 1u, __ATOMIC_RELAXED, __HIP_MEMORY_SCOPE_AGENT);
        unsigned target = 8u * (unsigned)(p + 1);
        while (ald(grpbar) < target) __builtin_amdgcn_s_sleep(2);
        asm volatile("" ::: "memory");
      }
      __syncthreads();
    }
  }
}

// ---------------- host ----------------

extern "C" void kernel_launch(void* const* d_in, const int* in_sizes, int n_in, void* d_out,
                              int out_size, void* d_ws, size_t ws_size, hipStream_t stream) {
  const float* tgt = (const float*)d_in[0];
  const float* src = (const float*)d_in[1];
  const float* W_ih = (const float*)d_in[2];
  const float* W_hh = (const float*)d_in[3];
  const float* b_ih = (const float*)d_in[4];
  const float* b_hh = (const float*)d_in[5];
  const float* Wq_w = (const float*)d_in[6];
  const float* Wq_b = (const float*)d_in[7];
  float* out = (float*)d_out;

  char* ws = (char*)d_ws;
  size_t off = 0;
  auto alloc = [&](size_t bytes) -> void* {
    void* p = ws + off;
    off = (off + bytes + 255) & ~(size_t)255;
    return p;
  };
  unsigned* bars = (unsigned*)alloc(2048 * 4);
  float* qkva = (float*)alloc((size_t)2 * 512 * QC * 4);
  unsigned short* hG = (unsigned short*)alloc((size_t)2 * 131072 * 2);
  __hip_bfloat16* Wcat = (__hip_bfloat16*)alloc((size_t)1024 * 512 * 2);
  __hip_bfloat16* Wq = (__hip_bfloat16*)alloc((size_t)576 * 256 * 2);
  float* biasq = (float*)alloc((size_t)576 * 4);
  __hip_bfloat16* tswz = (__hip_bfloat16*)alloc((size_t)128 * 131072 * 2);

  reset_bars<<<8, 256, 0, stream>>>(bars);
  prep_weights<<<2048, 256, 0, stream>>>(W_ih, W_hh, Wcat);
  prep_wq<<<576, 256, 0, stream>>>(Wq_w, Wq_b, Wq, biasq);
  prep_tgt<<<8192, 256, 0, stream>>>(tgt, tswz);

  hipFuncSetAttribute((const void*)persist, hipFuncAttributeMaxDynamicSharedMemorySize, DYN_LDS);

  const short8_v* tswz_p = (const short8_v*)tswz;
  const short8_v* Wcat_p = (const short8_v*)Wcat;
  const short8_v* Wq_p = (const short8_v*)Wq;
  const float* biasq_p = biasq;
  const float* bih_p = b_ih;
  const float* bhh_p = b_hh;
  unsigned short* hG_p = hG;
  float* qkva_p = qkva;
  float* out_p = out;
  const float* src_p = src;
  unsigned* bars_p = bars;
  void* kargs[] = {(void*)&tswz_p, (void*)&Wcat_p, (void*)&Wq_p,  (void*)&biasq_p,
                   (void*)&bih_p,  (void*)&bhh_p,  (void*)&hG_p,  (void*)&qkva_p,
                   (void*)&out_p,  (void*)&src_p,  (void*)&bars_p};
  hipLaunchCooperativeKernel((const void*)persist, dim3(256), dim3(512), kargs,
                             (unsigned)DYN_LDS, stream);
}

// Round 4
// 959.322 us; speedup vs baseline: 3.5046x; 1.4773x over previous
//
#include <hip/hip_runtime.h>
#include <hip/hip_bf16.h>

typedef short short8_v __attribute__((ext_vector_type(8)));
typedef float f32x4 __attribute__((ext_vector_type(4)));

#define QC 576  // padded qkva column stride: q[0,256) val[256,512) act[512,556) pad[556,576)

// fragment-swizzled layout: element (r,k) of an [R][K] operand ->
// tile (r/16, k/32), lane = (r%16) + 16*((k%32)/8), elem = k%8
__device__ __forceinline__ size_t swz_e(int r, int k, int KC) {
  return ((size_t)((r >> 4) * KC + (k >> 5)) * 64 + (r & 15) + (((k >> 3) & 3) << 4)) * 8 + (k & 7);
}

__device__ __forceinline__ float wave_sum(float v) {
#pragma unroll
  for (int off = 32; off > 0; off >>= 1) v += __shfl_xor(v, off);
  return v;
}

__device__ __forceinline__ float sigf(float x) { return 1.f / (1.f + __expf(-x)); }
// fast tanh via __expf: exact at saturation (e->inf -> 1, e->0 -> -1)
__device__ __forceinline__ float tfast(float x) {
  float e = __expf(2.f * x);
  return 1.f - 2.f / (e + 1.f);
}

// relaxed agent-scope atomics: L1-bypassing, coherent across XCDs
template <typename T>
__device__ __forceinline__ T ald(const T* p) {
  return __hip_atomic_load(p, __ATOMIC_RELAXED, __HIP_MEMORY_SCOPE_AGENT);
}
template <typename T>
__device__ __forceinline__ void ast(T* p, T v) {
  __hip_atomic_store(p, v, __ATOMIC_RELAXED, __HIP_MEMORY_SCOPE_AGENT);
}

// ---------------- prologue kernels (once per call) ----------------

__global__ void prep_weights(const float* __restrict__ W_ih, const float* __restrict__ W_hh,
                             __hip_bfloat16* __restrict__ Wcat) {
  int idx = blockIdx.x * blockDim.x + threadIdx.x;  // 1024*512
  if (idx >= 1024 * 512) return;
  int jj = idx >> 9, k = idx & 511;
  int chunk = jj >> 6, gate = (jj >> 4) & 3, r = jj & 15;
  int j = gate * 256 + chunk * 16 + r;
  float v = (k < 256) ? W_ih[j * 256 + k] : W_hh[j * 256 + (k - 256)];
  Wcat[swz_e(jj, k, 16)] = __float2bfloat16(v);
}

__global__ void prep_wq(const float* __restrict__ Wq_w, const float* __restrict__ Wq_b,
                        __hip_bfloat16* __restrict__ Wq, float* __restrict__ biasq) {
  int idx = blockIdx.x * blockDim.x + threadIdx.x;  // 576*256
  if (idx >= 576 * 256) return;
  int n = idx >> 8, k = idx & 255;
  int orig = (n < 256) ? n : (n < 556 ? n + 256 : -1);
  float v = (orig >= 0) ? Wq_w[orig * 256 + k] : 0.f;
  Wq[swz_e(n, k, 8)] = __float2bfloat16(v);
  if (k == 0) biasq[n] = (orig >= 0) ? Wq_b[orig] : 0.f;
}

__global__ void prep_tgt(const float* __restrict__ tgt, __hip_bfloat16* __restrict__ tswz) {
  for (size_t idx = (size_t)blockIdx.x * blockDim.x + threadIdx.x; idx < (size_t)128 * 131072;
       idx += (size_t)gridDim.x * blockDim.x) {
    int t = (int)(idx >> 17);
    int rem = (int)(idx & 131071);
    int b = rem >> 8, k = rem & 255;
    tswz[(size_t)t * 131072 + swz_e(b, k, 8)] = __float2bfloat16(tgt[idx]);
  }
}

__global__ void reset_bars(unsigned* __restrict__ bars) {
  int i = blockIdx.x * blockDim.x + threadIdx.x;
  if (i < 2048) bars[i] = 0u;
}

// ---------------- persistent cooperative kernel ----------------
// grid 256 x 512. Group m (0..31) = blocks {m + 32*cgrp}. Block (m,cgrp): 8 tape pairs
// (b = 16m+2cgrp+{0,1}, tp 0..3, one per wave), gates slice (rows 16m..+16, jj cols
// [128cgrp,128cgrp+128)), qkva tiles [qst,qst+qcnt).
// Phase p: gates(p)+LSTM->h(p) || qkva(p-1) || arrive || tape(p-2) || poll.
// LDS floats: tape 8*[64][16]f32x4 XOR-chunk-swizzled @0 (32768) ;
//   stash 8*384 @32768 (wsrs[2][64]f2, qn_s[64], dv_s[64]) ; gbuf 2048 @35840 ;
//   hstage 2048 @37888 ; total 39936 f = 159744 B
#define DYN_LDS 159744

__global__ __launch_bounds__(512, 2) void persist(
    const short8_v* __restrict__ tswz, const short8_v* __restrict__ Wcat,
    const short8_v* __restrict__ Wq, const float* __restrict__ biasq,
    const float* __restrict__ b_ih, const float* __restrict__ b_hh,
    unsigned short* __restrict__ hG,  // 2 x 131072 bf16 (frag-swizzled), dbuf
    float* __restrict__ qkva,         // 2 x 512*QC f32, dbuf
    float* __restrict__ out, const float* __restrict__ src, unsigned* __restrict__ bars) {
  extern __shared__ float lds[];
  const int tid = threadIdx.x;
  const int w = tid >> 6, lane = tid & 63;
  const int m = blockIdx.x & 31, cgrp = blockIdx.x >> 5;
  unsigned* grpbar = bars + m * 64;

  f32x4* Tc = (f32x4*)lds + (size_t)w * 1024;  // tape [64 rows][16 chunks], phys ch = c4^(row&15)
  float* S = lds + 32768 + w * 384;            // wsrs[2][128] ; qn_s@256 ; dv_s@320
  float* gbuf = lds + 35840;                   // [2][4][16][16]
  unsigned long long* hstage_u64 = (unsigned long long*)(lds + 37888);
  const short8_v* hstage_s8 = (const short8_v*)(lds + 37888);

  const int g = lane >> 4, c4 = lane & 15;

  // ---- tape pair identity + init ----
  const int b = 16 * m + 2 * cgrp + (w >> 2);
  const int tp = w & 3;
#pragma unroll
  for (int i = 0; i < 16; ++i) {
    int row = i * 4 + g;
    f32x4 v = *(const f32x4*)(src + (size_t)row * 131072 + b * 256 + tp * 64 + c4 * 4);
    Tc[row * 16 + (c4 ^ (row & 15))] = v;
  }
#pragma unroll
  for (int k = 0; k < 6; ++k) S[k * 64 + lane] = 0.f;  // zero stash (wsrs both, qn, dv)
  float rp = (lane == 0) ? 1.f : 0.f, wp = rp;

  // ---- epilogue roles: thread -> one h value (row = tid>>5, colLocal = tid&31) ----
  const int erow = tid >> 5, ecol = tid & 31;
  const int jh = 32 * cgrp + ecol;
  const float bI = b_ih[jh] + b_hh[jh];
  const float bF = b_ih[256 + jh] + b_hh[256 + jh];
  const float bG_ = b_ih[512 + jh] + b_hh[512 + jh];
  const float bO = b_ih[768 + jh] + b_hh[768 + jh];
  float c_reg = 0.f;
  const unsigned hIdx32 =
      (unsigned)(((m * 8 + cgrp) * 64 + erow + 16 * (ecol >> 3)) * 4 + ((ecol >> 1) & 3));

  // ---- qkva tile assignment ----
  const int qcnt = (cgrp < 4) ? 5 : 4;
  const int qst = (cgrp < 4) ? cgrp * 5 : 20 + (cgrp - 4) * 4;
  const int qtile = qst + w;  // valid if w < qcnt

  // ---- hoisted loop-invariant operands (registers) ----
  short8_v bFr[16];
#pragma unroll
  for (int kc = 0; kc < 16; ++kc) bFr[kc] = Wcat[((cgrp * 8 + w) * 16 + kc) * 64 + lane];
  short8_v bQ[8];
  float bqv = 0.f;
  int n0 = 0;
  if (w < qcnt) {
    n0 = qtile * 16 + (lane & 15);
    bqv = biasq[n0];
#pragma unroll
    for (int kc = 0; kc < 8; ++kc) bQ[kc] = Wq[(qtile * 8 + kc) * 64 + lane];
  }

#pragma unroll 1
  for (int p = 0; p <= 129; ++p) {
    const int hrd = (p + 1) & 1, hwr = p & 1;
    const int s = p - 2;  // tape step
    const int par = s & 1;

    // ---- early issue: tape's qkva-row loads (L3) ----
    float a_[11];
    f32x4 q4, val4;
    if (s >= 0) {
      const float* qrow = qkva + (size_t)(s & 1) * (512 * QC) + (size_t)b * QC;
#pragma unroll
      for (int j = 0; j < 11; ++j) a_[j] = ald(qrow + 512 + tp * 11 + j);
      unsigned long long u0 = ald((const unsigned long long*)(qrow + tp * 64 + c4 * 4));
      unsigned long long u1 = ald((const unsigned long long*)(qrow + tp * 64 + c4 * 4 + 2));
      unsigned long long v0 = ald((const unsigned long long*)(qrow + 256 + tp * 64 + c4 * 4));
      unsigned long long v1 = ald((const unsigned long long*)(qrow + 256 + tp * 64 + c4 * 4 + 2));
      float2 qa = __builtin_bit_cast(float2, u0), qb = __builtin_bit_cast(float2, u1);
      float2 va = __builtin_bit_cast(float2, v0), vb = __builtin_bit_cast(float2, v1);
      q4 = (f32x4){qa.x, qa.y, qb.x, qb.y};
      val4 = (f32x4){va.x, va.y, vb.x, vb.y};
    }
    // ---- gates A operands ----
    short8_v aF[8];
    if (p < 128) {
      const short8_v* xg = tswz + (size_t)p * 16384;
#pragma unroll
      for (int kc = 0; kc < 8; ++kc) aF[kc] = xg[(m * 8 + kc) * 64 + lane];
    }
    // ---- stage h(p-1) into LDS ----
    if (p >= 1 && p <= 128) {
      const unsigned long long* hsrc = (const unsigned long long*)(hG + (size_t)hrd * 131072) +
                                       ((size_t)(m * 8 + w) * 64 + lane) * 2;
      unsigned long long lo = ald(hsrc), hi = ald(hsrc + 1);
      hstage_u64[((size_t)w * 64 + lane) * 2] = lo;
      hstage_u64[((size_t)w * 64 + lane) * 2 + 1] = hi;
    }
    __syncthreads();  // hstage ready; prev-phase gbuf/hstage uses complete
    // ---- gates MFMA -> gbuf ----
    if (p < 128) {
      f32x4 acc = {0.f, 0.f, 0.f, 0.f};
#pragma unroll
      for (int kc = 0; kc < 8; ++kc)
        acc = __builtin_amdgcn_mfma_f32_16x16x32_bf16(aF[kc], bFr[kc], acc, 0, 0, 0);
      if (p > 0) {
#pragma unroll
        for (int kc = 8; kc < 16; ++kc) {
          short8_v a = hstage_s8[(kc - 8) * 64 + lane];
          acc = __builtin_amdgcn_mfma_f32_16x16x32_bf16(a, bFr[kc], acc, 0, 0, 0);
        }
      }
      int cl = w >> 2, gate = w & 3;
#pragma unroll
      for (int r = 0; r < 4; ++r)
        gbuf[((cl * 4 + gate) * 16 + ((lane >> 4) * 4 + r)) * 16 + (lane & 15)] = acc[r];
    }
    __syncthreads();  // gbuf ready
    // ---- LSTM epilogue -> h(p) ----
    if (p < 128) {
      float gi = gbuf[(((ecol >> 4) * 4 + 0) * 16 + erow) * 16 + (ecol & 15)] + bI;
      float gf = gbuf[(((ecol >> 4) * 4 + 1) * 16 + erow) * 16 + (ecol & 15)] + bF;
      float gg = gbuf[(((ecol >> 4) * 4 + 2) * 16 + erow) * 16 + (ecol & 15)] + bG_;
      float go = gbuf[(((ecol >> 4) * 4 + 3) * 16 + erow) * 16 + (ecol & 15)] + bO;
      float cc = sigf(gf) * c_reg + sigf(gi) * tfast(gg);
      c_reg = cc;
      float hh = sigf(go) * tfast(cc);
      __hip_bfloat16 hb16 = __float2bfloat16(hh);
      unsigned own = (unsigned)(*(unsigned short*)&hb16);
      unsigned other = (unsigned)__shfl_xor((int)own, 1) & 0xFFFFu;
      if ((ecol & 1) == 0) {
        unsigned pack = (other << 16) | own;
        ast((unsigned*)(hG + (size_t)hwr * 131072) + hIdx32, pack);
      }
    }
    // ---- qkva MFMA for step p-1 ----
    if (p >= 1 && p <= 128 && w < qcnt) {
      f32x4 qa = {0.f, 0.f, 0.f, 0.f};
#pragma unroll
      for (int kc = 0; kc < 8; ++kc)
        qa = __builtin_amdgcn_mfma_f32_16x16x32_bf16(hstage_s8[kc * 64 + lane], bQ[kc], qa, 0, 0, 0);
      float* qw = qkva + (size_t)((p - 1) & 1) * (512 * QC);
#pragma unroll
      for (int r = 0; r < 4; ++r)
        ast(&qw[(size_t)(16 * m + (lane >> 4) * 4 + r) * QC + n0], qa[r] + bqv);
    }
    // ---- drain stores, arrive at group barrier, THEN do tape (hides barrier) ----
    asm volatile("s_waitcnt vmcnt(0)" ::: "memory");
    __syncthreads();
    if (tid == 0 && p < 129)
      __hip_atomic_fetch_add(grpbar, 1u, __ATOMIC_RELAXED, __HIP_MEMORY_SCOPE_AGENT);
    // ---- tape compute for step s (consumes qkva(s), barrier'd end of phase p-1) ----
    if (s >= 0) {
      float m1 = fmaxf(fmaxf(a_[0], a_[1]), fmaxf(a_[2], a_[3]));
      float e0 = __expf(a_[0] - m1), e1 = __expf(a_[1] - m1), e2 = __expf(a_[2] - m1),
            e3 = __expf(a_[3] - m1);
      float inv = 1.f / (e0 + e1 + e2 + e3);
      float rd0 = e0 * inv, rd1 = e1 * inv, rd2 = e2 * inv, rd3 = e3 * inv;
      float m2 = fmaxf(fmaxf(a_[4], a_[5]), fmaxf(a_[6], a_[7]));
      float f0 = __expf(a_[4] - m2), f1 = __expf(a_[5] - m2), f2 = __expf(a_[6] - m2),
            f3 = __expf(a_[7] - m2);
      float inv2 = 1.f / (f0 + f1 + f2 + f3);
      float wd0 = f0 * inv2, wd1 = f1 * inv2, wd2 = f2 * inv2, wd3 = f3 * inv2;
      float rwe0 = sigf(a_[8]), rwe1 = sigf(a_[9]), rwe2 = sigf(a_[10]);
      // qn: normalize q over 64 cols (lane holds 4 cols; reduce over c4 groups)
      float ss = q4[0] * q4[0] + q4[1] * q4[1] + q4[2] * q4[2] + q4[3] * q4[3];
#pragma unroll
      for (int off = 1; off < 16; off <<= 1) ss += __shfl_xor(ss, off);
      float qninv = 1.f / fmaxf(sqrtf(ss), 1e-12f);
      f32x4 qn4 = q4 * qninv;
      // stage per-row {wp, rs} (lane=row) and qn (g==0 lanes)
      *(float2*)&S[par * 128 + lane * 2] = make_float2(wp, rp * rwe0);
      if (g == 0) *(f32x4*)&S[256 + c4 * 4] = qn4;
      f32x4 dv4 = *(const f32x4*)&S[320 + c4 * 4];  // pending rank-1 (prev phase)
      // row pass: apply pending, write back, reduce oldval & rval
      f32x4 oa = {0.f, 0.f, 0.f, 0.f}, ra = oa;
#pragma unroll
      for (int i = 0; i < 16; ++i) {
        int row = i * 4 + g;
        float2 wrO = *(const float2*)&S[(par ^ 1) * 128 + row * 2];
        float2 wrN = *(const float2*)&S[par * 128 + row * 2];
        int ti = row * 16 + (c4 ^ (row & 15));
        f32x4 v = Tc[ti];
        v += wrO.x * dv4;
        Tc[ti] = v;
        oa += wrN.x * v;
        ra += wrN.y * v;
      }
#pragma unroll
      for (int off = 16; off <= 32; off <<= 1) {
        f32x4 t;
        t[0] = __shfl_xor(oa[0], off); t[1] = __shfl_xor(oa[1], off);
        t[2] = __shfl_xor(oa[2], off); t[3] = __shfl_xor(oa[3], off);
        oa += t;
        t[0] = __shfl_xor(ra[0], off); t[1] = __shfl_xor(ra[1], off);
        t[2] = __shfl_xor(ra[2], off); t[3] = __shfl_xor(ra[3], off);
        ra += t;
      }
      f32x4 dvn = val4 * rwe1 - oa * rwe2;
      if (g == 0) {
        *(f32x4*)&S[320 + c4 * 4] = dvn;  // next phase's pending
        *(f32x4*)(out + (size_t)s * 131072 + b * 256 + tp * 64 + c4 * 4) = ra;
      }
      // col pass: jq[row=lane] = sum_c T[row][c]*qn[c]
      float jq = 0.f;
#pragma unroll
      for (int j = 0; j < 16; ++j) {
        f32x4 v = Tc[lane * 16 + (j ^ (lane & 15))];
        f32x4 qv = *(const f32x4*)&S[256 + j * 4];
        jq += v[0] * qv[0] + v[1] * qv[1] + v[2] * qv[2] + v[3] * qv[3];
      }
      float jsum = wave_sum(jq * jq);
      float jp = jq / fmaxf(sqrtf(jsum), 1e-12f);
      // roll(x,1)[i]=x[i-1] (next_*), roll(x,-1)[i]=x[i+1] (prev_*)
      float next_w = __shfl(wp, (lane + 63) & 63);
      float prev_w = __shfl(wp, (lane + 1) & 63);
      float next_r = __shfl(rp, (lane + 63) & 63);
      float prev_r = __shfl(rp, (lane + 1) & 63);
      wp = prev_w * wd0 + wp * wd1 + next_w * wd2 + jp * wd3;
      rp = prev_r * rd0 + rp * rd1 + next_r * rd2 + jp * rd3;
    }
    // ---- wait for group (mostly already satisfied: tape overlapped the skew) ----
    if (p < 129) {
      __syncthreads();
      if (tid == 0) {
        unsigned target = 8u * (unsigned)(p + 1);
        while (ald(grpbar) < target) __builtin_amdgcn_s_sleep(2);
        asm volatile("" ::: "memory");
      }
      __syncthreads();
    }
  }
}

// ---------------- host ----------------

extern "C" void kernel_launch(void* const* d_in, const int* in_sizes, int n_in, void* d_out,
                              int out_size, void* d_ws, size_t ws_size, hipStream_t stream) {
  const float* tgt = (const float*)d_in[0];
  const float* src = (const float*)d_in[1];
  const float* W_ih = (const float*)d_in[2];
  const float* W_hh = (const float*)d_in[3];
  const float* b_ih = (const float*)d_in[4];
  const float* b_hh = (const float*)d_in[5];
  const float* Wq_w = (const float*)d_in[6];
  const float* Wq_b = (const float*)d_in[7];
  float* out = (float*)d_out;

  char* ws = (char*)d_ws;
  size_t off = 0;
  auto alloc = [&](size_t bytes) -> void* {
    void* p = ws + off;
    off = (off + bytes + 255) & ~(size_t)255;
    return p;
  };
  unsigned* bars = (unsigned*)alloc(2048 * 4);
  float* qkva = (float*)alloc((size_t)2 * 512 * QC * 4);
  unsigned short* hG = (unsigned short*)alloc((size_t)2 * 131072 * 2);
  __hip_bfloat16* Wcat = (__hip_bfloat16*)alloc((size_t)1024 * 512 * 2);
  __hip_bfloat16* Wq = (__hip_bfloat16*)alloc((size_t)576 * 256 * 2);
  float* biasq = (float*)alloc((size_t)576 * 4);
  __hip_bfloat16* tswz = (__hip_bfloat16*)alloc((size_t)128 * 131072 * 2);

  reset_bars<<<8, 256, 0, stream>>>(bars);
  prep_weights<<<2048, 256, 0, stream>>>(W_ih, W_hh, Wcat);
  prep_wq<<<576, 256, 0, stream>>>(Wq_w, Wq_b, Wq, biasq);
  prep_tgt<<<8192, 256, 0, stream>>>(tgt, tswz);

  hipFuncSetAttribute((const void*)persist, hipFuncAttributeMaxDynamicSharedMemorySize, DYN_LDS);

  const short8_v* tswz_p = (const short8_v*)tswz;
  const short8_v* Wcat_p = (const short8_v*)Wcat;
  const short8_v* Wq_p = (const short8_v*)Wq;
  const float* biasq_p = biasq;
  const float* bih_p = b_ih;
  const float* bhh_p = b_hh;
  unsigned short* hG_p = hG;
  float* qkva_p = qkva;
  float* out_p = out;
  const float* src_p = src;
  unsigned* bars_p = bars;
  void* kargs[] = {(void*)&tswz_p, (void*)&Wcat_p, (void*)&Wq_p,  (void*)&biasq_p,
                   (void*)&bih_p,  (void*)&bhh_p,  (void*)&hG_p,  (void*)&qkva_p,
                   (void*)&out_p,  (void*)&src_p,  (void*)&bars_p};
  hipLaunchCooperativeKernel((const void*)persist, dim3(256), dim3(512), kargs,
                             (unsigned)DYN_LDS, stream);
}